// Round 1
// baseline (458.966 us; speedup 1.0000x reference)
//
#include <hip/hip_runtime.h>
#include <hip/hip_bf16.h>

typedef __bf16 bf16;
typedef __bf16 bf16x8 __attribute__((ext_vector_type(8)));
typedef __bf16 bf16x4 __attribute__((ext_vector_type(4)));
typedef float f32x4 __attribute__((ext_vector_type(4)));

#define HIDDEN 2048
#define SEQ 2048
#define NH 16
#define QL 1536
#define KVL 512
#define DQK 192
#define ATTN_SCALE 0.07216878364870323f  // 1/sqrt(192)

// ---------------- fp32 -> bf16 convert (vectorized) ----------------
__global__ void k_cvt(const float* __restrict__ in, bf16* __restrict__ out, int n) {
  int i = blockIdx.x * blockDim.x + threadIdx.x;
  int base = i * 4;
  if (base < n) {
    float4 v = *(const float4*)(in + base);
    bf16x4 o = { (bf16)v.x, (bf16)v.y, (bf16)v.z, (bf16)v.w };
    *(bf16x4*)(out + base) = o;
  }
}

// ---------------- W[K][N] fp32 -> Wt[N][K] bf16 (LDS tile transpose) ----------------
__global__ void k_transpose(const float* __restrict__ W, bf16* __restrict__ Wt, int K, int N) {
  __shared__ float tile[32][33];
  int n0 = blockIdx.x * 32, k0 = blockIdx.y * 32;
  int tid = threadIdx.x;
  int cc = tid & 31, rr = tid >> 5;  // 8 rows per iter, 4 iters
#pragma unroll
  for (int it = 0; it < 4; ++it) {
    int r = it * 8 + rr;
    tile[r][cc] = W[(size_t)(k0 + r) * N + n0 + cc];
  }
  __syncthreads();
#pragma unroll
  for (int it = 0; it < 4; ++it) {
    int r = it * 8 + rr;  // n-local
    Wt[(size_t)(n0 + r) * K + k0 + cc] = (bf16)tile[cc][r];
  }
}

// ---------------- bf16 GEMM: C[M][N] = A[M][K] @ Bt[N][K]^T ----------------
// 128x128 tile, BK=64, 4 waves (2x2), each wave 64x64 via 4x4 16x16x32 MFMA frags.
// LDS rows padded +8 bf16 (stride 144B: 16B-aligned, 4-bank rotation -> free 2-way conflicts).
__global__ __launch_bounds__(256) void k_gemm(const bf16* __restrict__ A, const bf16* __restrict__ Bt,
                                              bf16* __restrict__ Cb, float* __restrict__ Cf,
                                              int M, int N, int K) {
  __shared__ __align__(16) bf16 As[128 * 72];
  __shared__ __align__(16) bf16 Bs[128 * 72];
  int tid = threadIdx.x, lane = tid & 63, w = tid >> 6;
  int wr = w >> 1, wc = w & 1;
  int m0 = blockIdx.x * 128, n0 = blockIdx.y * 128;
  int l15 = lane & 15, l4 = lane >> 4;
  f32x4 acc[4][4] = {};
  for (int k0 = 0; k0 < K; k0 += 64) {
#pragma unroll
    for (int it = 0; it < 4; ++it) {
      int idx = it * 256 + tid;
      int row = idx >> 3, cg = (idx & 7) * 8;
      *(int4*)&As[row * 72 + cg] = *(const int4*)&A[(size_t)(m0 + row) * K + k0 + cg];
      int4 bv = {0, 0, 0, 0};
      if (n0 + row < N) bv = *(const int4*)&Bt[(size_t)(n0 + row) * K + k0 + cg];
      *(int4*)&Bs[row * 72 + cg] = bv;
    }
    __syncthreads();
#pragma unroll
    for (int kk = 0; kk < 2; ++kk) {
      bf16x8 af[4], bfr[4];
#pragma unroll
      for (int m = 0; m < 4; ++m)
        af[m] = *(const bf16x8*)&As[(wr * 64 + m * 16 + l15) * 72 + kk * 32 + l4 * 8];
#pragma unroll
      for (int n = 0; n < 4; ++n)
        bfr[n] = *(const bf16x8*)&Bs[(wc * 64 + n * 16 + l15) * 72 + kk * 32 + l4 * 8];
#pragma unroll
      for (int m = 0; m < 4; ++m)
#pragma unroll
        for (int n = 0; n < 4; ++n)
          acc[m][n] = __builtin_amdgcn_mfma_f32_16x16x32_bf16(af[m], bfr[n], acc[m][n], 0, 0, 0);
    }
    __syncthreads();
  }
  // epilogue: D layout col = lane&15, row = (lane>>4)*4 + reg
#pragma unroll
  for (int m = 0; m < 4; ++m)
#pragma unroll
    for (int n = 0; n < 4; ++n)
#pragma unroll
      for (int r = 0; r < 4; ++r) {
        int grow = m0 + wr * 64 + m * 16 + l4 * 4 + r;
        int gcol = n0 + wc * 64 + n * 16 + l15;
        if (gcol < N) {
          float v = acc[m][n][r];
          if (Cf) Cf[(size_t)grow * N + gcol] = v;
          else Cb[(size_t)grow * N + gcol] = (bf16)v;
        }
      }
}

// ---------------- block-wide sum reduce (256 threads) ----------------
__device__ inline float block_reduce_sum(float v, float* red) {
#pragma unroll
  for (int off = 1; off < 64; off <<= 1) v += __shfl_xor(v, off);
  int w = threadIdx.x >> 6;
  if ((threadIdx.x & 63) == 0) red[w] = v;
  __syncthreads();
  return red[0] + red[1] + red[2] + red[3];
}

// ---------------- RMSNorm (q path, D=1536) fp32 -> bf16 ----------------
__global__ void k_rms_q(const float* __restrict__ X, const float* __restrict__ g, bf16* __restrict__ out) {
  __shared__ float red[4];
  int row = blockIdx.x, tid = threadIdx.x;
  float v[6];
  float ss = 0.f;
#pragma unroll
  for (int j = 0; j < 6; ++j) {
    v[j] = X[(size_t)row * QL + tid + j * 256];
    ss += v[j] * v[j];
  }
  float tot = block_reduce_sum(ss, red);
  float rs = rsqrtf(tot / (float)QL + 1e-6f);
#pragma unroll
  for (int j = 0; j < 6; ++j) {
    int c = tid + j * 256;
    out[(size_t)row * QL + c] = (bf16)(v[j] * rs * g[c]);
  }
}

// ---------------- RMSNorm (kv path, norm first 512 cols of 576) + rope passthrough ----------------
__global__ void k_rms_kv(const float* __restrict__ KVC, const float* __restrict__ g,
                         bf16* __restrict__ outn, bf16* __restrict__ outr) {
  __shared__ float red[4];
  int row = blockIdx.x, tid = threadIdx.x;
  float v0 = KVC[(size_t)row * 576 + tid];
  float v1 = KVC[(size_t)row * 576 + tid + 256];
  float tot = block_reduce_sum(v0 * v0 + v1 * v1, red);
  float rs = rsqrtf(tot / (float)KVL + 1e-6f);
  outn[(size_t)row * KVL + tid] = (bf16)(v0 * rs * g[tid]);
  outn[(size_t)row * KVL + tid + 256] = (bf16)(v1 * rs * g[tid + 256]);
  if (tid < 64) outr[row * 64 + tid] = (bf16)KVC[(size_t)row * 576 + 512 + tid];
}

// ---------------- fused causal flash attention ----------------
// grid = 512: h = bid&15, i = bid>>4, qb = i<16 ? i : 47-i (balances causal work across
// co-resident block pairs). 4 waves x 16 q-rows, KVBLK=64.
__global__ __launch_bounds__(256) void k_attn(const bf16* __restrict__ Q, const bf16* __restrict__ KV,
                                              const bf16* __restrict__ KR, bf16* __restrict__ O) {
  __shared__ __align__(16) bf16 Ks[64 * 200];   // [kvpos][192+8]
  __shared__ __align__(16) bf16 Vs[128 * 72];   // [feat][64+8]  (V transposed)
  __shared__ __align__(16) bf16 Ps[4 * 16 * 72];  // per-wave P tile [16][64+8]
  int bid = blockIdx.x;
  int h = bid & 15, i = bid >> 4;
  int qb = (i < 16) ? i : 47 - i;
  int q0 = qb * 64;
  int tid = threadIdx.x, lane = tid & 63, w = tid >> 6;
  int l15 = lane & 15, l4 = lane >> 4;
  bf16* Pw = Ps + w * 16 * 72;

  // Q fragments in registers: rows q0 + w*16 + (lane&15), 6 K-steps of 32 over d=192
  bf16x8 aq[6];
  int qrow = q0 + w * 16 + l15;
#pragma unroll
  for (int ks = 0; ks < 6; ++ks)
    aq[ks] = *(const bf16x8*)&Q[(size_t)qrow * 3072 + h * 192 + ks * 32 + l4 * 8];

  f32x4 oacc[8] = {};
  float m[4] = {-1e30f, -1e30f, -1e30f, -1e30f};
  float lsum[4] = {};
  int nt = qb + 1;
  for (int t = 0; t < nt; ++t) {
    // stage K tile [64][192]: cols 0..127 = k_nope (KV col h*256+), 128..191 = k_rope
#pragma unroll
    for (int it = 0; it < 6; ++it) {
      int idx = it * 256 + tid;
      int r = idx / 24, gg = idx % 24;
      int p = t * 64 + r;
      int4 val;
      if (gg < 16) val = *(const int4*)&KV[(size_t)p * 4096 + h * 256 + gg * 8];
      else         val = *(const int4*)&KR[(size_t)p * 64 + (gg - 16) * 8];
      *(int4*)&Ks[r * 200 + gg * 8] = val;
    }
    // stage V transposed: Vs[feat][kvpos]
#pragma unroll
    for (int it = 0; it < 4; ++it) {
      int idx = it * 256 + tid;
      int r = idx >> 4, dg = idx & 15;
      int p = t * 64 + r;
      union { int4 i4; bf16 h8[8]; } u;
      u.i4 = *(const int4*)&KV[(size_t)p * 4096 + h * 256 + 128 + dg * 8];
#pragma unroll
      for (int j = 0; j < 8; ++j) Vs[(dg * 8 + j) * 72 + r] = u.h8[j];
    }
    __syncthreads();

    // S = Q @ K^T : 16x64 per wave
    f32x4 sacc[4] = {};
#pragma unroll
    for (int ks = 0; ks < 6; ++ks)
#pragma unroll
      for (int n = 0; n < 4; ++n) {
        bf16x8 bk = *(const bf16x8*)&Ks[(n * 16 + l15) * 200 + ks * 32 + l4 * 8];
        sacc[n] = __builtin_amdgcn_mfma_f32_16x16x32_bf16(aq[ks], bk, sacc[n], 0, 0, 0);
      }

    // scale + causal mask (only diagonal tile needs masking)
    bool lastt = (t == nt - 1);
#pragma unroll
    for (int n = 0; n < 4; ++n)
#pragma unroll
      for (int r = 0; r < 4; ++r) {
        float v = sacc[n][r] * ATTN_SCALE;
        if (lastt) {
          int col = t * 64 + n * 16 + l15;
          int rowg = q0 + w * 16 + l4 * 4 + r;
          if (col > rowg) v = -1e30f;
        }
        sacc[n][r] = v;
      }

    // online softmax: row = (lane>>4)*4 + r, cols spread over 16 lanes (lane&15) x 4 nfrags
    float pv[4][4];
#pragma unroll
    for (int r = 0; r < 4; ++r) {
      float mx = fmaxf(fmaxf(sacc[0][r], sacc[1][r]), fmaxf(sacc[2][r], sacc[3][r]));
      mx = fmaxf(mx, __shfl_xor(mx, 1));
      mx = fmaxf(mx, __shfl_xor(mx, 2));
      mx = fmaxf(mx, __shfl_xor(mx, 4));
      mx = fmaxf(mx, __shfl_xor(mx, 8));
      float mn = fmaxf(m[r], mx);
      float alpha = __expf(m[r] - mn);
      m[r] = mn;
      float rsum = 0.f;
#pragma unroll
      for (int n = 0; n < 4; ++n) { pv[n][r] = __expf(sacc[n][r] - mn); rsum += pv[n][r]; }
      rsum += __shfl_xor(rsum, 1);
      rsum += __shfl_xor(rsum, 2);
      rsum += __shfl_xor(rsum, 4);
      rsum += __shfl_xor(rsum, 8);
      lsum[r] = lsum[r] * alpha + rsum;
#pragma unroll
      for (int vf = 0; vf < 8; ++vf) oacc[vf][r] *= alpha;
    }

    // P -> bf16 -> per-wave LDS (D-layout scatter), then PV MFMA
#pragma unroll
    for (int n = 0; n < 4; ++n)
#pragma unroll
      for (int r = 0; r < 4; ++r)
        Pw[(l4 * 4 + r) * 72 + n * 16 + l15] = (bf16)pv[n][r];

#pragma unroll
    for (int ks = 0; ks < 2; ++ks) {
      bf16x8 ap = *(const bf16x8*)&Pw[l15 * 72 + ks * 32 + l4 * 8];
#pragma unroll
      for (int vf = 0; vf < 8; ++vf) {
        bf16x8 bv = *(const bf16x8*)&Vs[(vf * 16 + l15) * 72 + ks * 32 + l4 * 8];
        oacc[vf] = __builtin_amdgcn_mfma_f32_16x16x32_bf16(ap, bv, oacc[vf], 0, 0, 0);
      }
    }
    __syncthreads();  // before next tile overwrites Ks/Vs
  }

  // epilogue: O[row][h*128 + feat] = oacc / lsum
#pragma unroll
  for (int vf = 0; vf < 8; ++vf)
#pragma unroll
    for (int r = 0; r < 4; ++r) {
      int rowg = q0 + w * 16 + l4 * 4 + r;
      int col = h * 128 + vf * 16 + l15;
      O[(size_t)rowg * 2048 + col] = (bf16)(oacc[vf][r] / lsum[r]);
    }
}

extern "C" void kernel_launch(void* const* d_in, const int* in_sizes, int n_in,
                              void* d_out, int out_size, void* d_ws, size_t ws_size,
                              hipStream_t stream) {
  (void)in_sizes; (void)n_in; (void)out_size; (void)ws_size;
  const float* hidden = (const float*)d_in[0];
  // d_in[1] = attention_mask (causal, computed inline -> unused)
  const float* Wqa  = (const float*)d_in[2];
  const float* gqa  = (const float*)d_in[3];
  const float* Wqb  = (const float*)d_in[4];
  const float* Wkva = (const float*)d_in[5];
  const float* gkva = (const float*)d_in[6];
  const float* Wkvb = (const float*)d_in[7];
  const float* Wo   = (const float*)d_in[8];
  float* out = (float*)d_out;

  char* ws = (char*)d_ws;
  size_t off = 0;
  auto alloc = [&](size_t bytes) {
    char* p = ws + off;
    off += (bytes + 255) & ~(size_t)255;
    return p;
  };
  bf16* Xb     = (bf16*)alloc((size_t)SEQ * HIDDEN * 2);
  bf16* WqaT   = (bf16*)alloc((size_t)QL * HIDDEN * 2);
  bf16* WqbT   = (bf16*)alloc((size_t)(NH * DQK) * QL * 2);
  bf16* WkvaT  = (bf16*)alloc((size_t)576 * HIDDEN * 2);
  bf16* WkvbT  = (bf16*)alloc((size_t)4096 * KVL * 2);
  bf16* WoT    = (bf16*)alloc((size_t)2048 * 2048 * 2);
  float* qa    = (float*)alloc((size_t)SEQ * QL * 4);
  float* kvc   = (float*)alloc((size_t)SEQ * 576 * 4);
  bf16* qc     = (bf16*)alloc((size_t)SEQ * QL * 2);
  bf16* kvn    = (bf16*)alloc((size_t)SEQ * KVL * 2);
  bf16* krope  = (bf16*)alloc((size_t)SEQ * 64 * 2);
  bf16* Qm     = (bf16*)alloc((size_t)SEQ * 3072 * 2);
  bf16* KVm    = (bf16*)alloc((size_t)SEQ * 4096 * 2);
  bf16* Om     = (bf16*)alloc((size_t)SEQ * 2048 * 2);

  // 1. hidden -> bf16
  k_cvt<<<(SEQ * HIDDEN / 4 + 255) / 256, 256, 0, stream>>>(hidden, Xb, SEQ * HIDDEN);
  // 2. weight transposes fp32[K][N] -> bf16[N][K]
  k_transpose<<<dim3(QL / 32, HIDDEN / 32), 256, 0, stream>>>(Wqa, WqaT, HIDDEN, QL);
  k_transpose<<<dim3(3072 / 32, QL / 32), 256, 0, stream>>>(Wqb, WqbT, QL, 3072);
  k_transpose<<<dim3(576 / 32, HIDDEN / 32), 256, 0, stream>>>(Wkva, WkvaT, HIDDEN, 576);
  k_transpose<<<dim3(4096 / 32, KVL / 32), 256, 0, stream>>>(Wkvb, WkvbT, KVL, 4096);
  k_transpose<<<dim3(2048 / 32, 2048 / 32), 256, 0, stream>>>(Wo, WoT, 2048, 2048);
  // 3. LoRA-A projections (fp32 out for RMSNorm)
  k_gemm<<<dim3(16, 12), 256, 0, stream>>>(Xb, WqaT, nullptr, qa, SEQ, QL, HIDDEN);
  k_gemm<<<dim3(16, 5), 256, 0, stream>>>(Xb, WkvaT, nullptr, kvc, SEQ, 576, HIDDEN);
  // 4. RMSNorms
  k_rms_q<<<SEQ, 256, 0, stream>>>(qa, gqa, qc);
  k_rms_kv<<<SEQ, 256, 0, stream>>>(kvc, gkva, kvn, krope);
  // 5. LoRA-B projections
  k_gemm<<<dim3(16, 24), 256, 0, stream>>>(qc, WqbT, Qm, nullptr, SEQ, 3072, QL);
  k_gemm<<<dim3(16, 32), 256, 0, stream>>>(kvn, WkvbT, KVm, nullptr, SEQ, 4096, KVL);
  // 6. fused causal attention
  k_attn<<<512, 256, 0, stream>>>(Qm, KVm, krope, Om);
  // 7. output projection -> fp32 d_out
  k_gemm<<<dim3(16, 16), 256, 0, stream>>>(Om, WoT, nullptr, out, SEQ, 2048, 2048);
}

// Round 2
// 324.336 us; speedup vs baseline: 1.4151x; 1.4151x over previous
//
#include <hip/hip_runtime.h>
#include <hip/hip_bf16.h>

typedef __bf16 bf16;
typedef __bf16 bf16x8 __attribute__((ext_vector_type(8)));
typedef __bf16 bf16x4 __attribute__((ext_vector_type(4)));
typedef float f32x4 __attribute__((ext_vector_type(4)));

#define HIDDEN 2048
#define SEQ 2048
#define NH 16
#define QL 1536
#define KVL 512
#define DQK 192
#define ATTN_SCALE 0.07216878364870323f  // 1/sqrt(192)

// ---- global -> LDS direct load, 16B per lane. Dest = uniform base + lane*16. ----
__device__ __forceinline__ void gload_lds16(const void* g, void* l) {
  typedef const __attribute__((address_space(1))) void* gp_t;
  typedef __attribute__((address_space(3))) void* lp_t;
  __builtin_amdgcn_global_load_lds((gp_t)(unsigned long long)g,
                                   (lp_t)(unsigned int)(unsigned long long)l, 16, 0, 0);
}

// ---------------- fp32 -> bf16 convert (vectorized) ----------------
__global__ void k_cvt(const float* __restrict__ in, bf16* __restrict__ out, int n) {
  int i = blockIdx.x * blockDim.x + threadIdx.x;
  int base = i * 4;
  if (base < n) {
    float4 v = *(const float4*)(in + base);
    bf16x4 o = { (bf16)v.x, (bf16)v.y, (bf16)v.z, (bf16)v.w };
    *(bf16x4*)(out + base) = o;
  }
}

// ---------------- W[K][N] fp32 -> Wt[N][K] bf16 (LDS tile transpose) ----------------
__global__ void k_transpose(const float* __restrict__ W, bf16* __restrict__ Wt, int K, int N) {
  __shared__ float tile[32][33];
  int n0 = blockIdx.x * 32, k0 = blockIdx.y * 32;
  int tid = threadIdx.x;
  int cc = tid & 31, rr = tid >> 5;
#pragma unroll
  for (int it = 0; it < 4; ++it) {
    int r = it * 8 + rr;
    tile[r][cc] = W[(size_t)(k0 + r) * N + n0 + cc];
  }
  __syncthreads();
#pragma unroll
  for (int it = 0; it < 4; ++it) {
    int r = it * 8 + rr;
    Wt[(size_t)(n0 + r) * K + k0 + cc] = (bf16)tile[cc][r];
  }
}

// ---------------- bf16 GEMM (m97 structure): C[M][N] = A[M][K] @ Bt[N][K]^T ----------------
// 128x128 tile, BK=64, 4 waves (2x2), global_load_lds width-16 staging into linear LDS.
__global__ __launch_bounds__(256) void k_gemm(const bf16* __restrict__ A, const bf16* __restrict__ Bt,
                                              bf16* __restrict__ Cb, float* __restrict__ Cf,
                                              int M, int N, int K) {
  __shared__ __align__(16) bf16 As[128 * 64];
  __shared__ __align__(16) bf16 Bs[128 * 64];
  int tid = threadIdx.x, lane = tid & 63, w = tid >> 6;
  int wr = w >> 1, wc = w & 1;
  int m0 = blockIdx.x * 128, n0 = blockIdx.y * 128;
  int l15 = lane & 15, l4 = lane >> 4;
  f32x4 acc[4][4] = {};
  for (int k0 = 0; k0 < K; k0 += 64) {
    // stage A,B tiles: each wave issues 4 chunks of 1KB per tile
#pragma unroll
    for (int i = 0; i < 4; ++i) {
      int c = w * 4 + i;
      int row = c * 8 + (lane >> 3);
      int col = (lane & 7) * 8;
      gload_lds16(&A[(size_t)(m0 + row) * K + k0 + col], &As[c * 512]);
      gload_lds16(&Bt[(size_t)(n0 + row) * K + k0 + col], &Bs[c * 512]);
    }
    __syncthreads();
#pragma unroll
    for (int kk = 0; kk < 2; ++kk) {
      bf16x8 af[4], bfr[4];
#pragma unroll
      for (int m = 0; m < 4; ++m)
        af[m] = *(const bf16x8*)&As[(wr * 64 + m * 16 + l15) * 64 + kk * 32 + l4 * 8];
#pragma unroll
      for (int n = 0; n < 4; ++n)
        bfr[n] = *(const bf16x8*)&Bs[(wc * 64 + n * 16 + l15) * 64 + kk * 32 + l4 * 8];
      __builtin_amdgcn_s_setprio(1);
#pragma unroll
      for (int m = 0; m < 4; ++m)
#pragma unroll
        for (int n = 0; n < 4; ++n)
          acc[m][n] = __builtin_amdgcn_mfma_f32_16x16x32_bf16(af[m], bfr[n], acc[m][n], 0, 0, 0);
      __builtin_amdgcn_s_setprio(0);
    }
    __syncthreads();
  }
#pragma unroll
  for (int m = 0; m < 4; ++m)
#pragma unroll
    for (int n = 0; n < 4; ++n)
#pragma unroll
      for (int r = 0; r < 4; ++r) {
        int grow = m0 + wr * 64 + m * 16 + l4 * 4 + r;
        int gcol = n0 + wc * 64 + n * 16 + l15;
        if (gcol < N) {
          float v = acc[m][n][r];
          if (Cf) Cf[(size_t)grow * N + gcol] = v;
          else Cb[(size_t)grow * N + gcol] = (bf16)v;
        }
      }
}

// ---------------- block-wide sum reduce (256 threads) ----------------
__device__ inline float block_reduce_sum(float v, float* red) {
#pragma unroll
  for (int off = 1; off < 64; off <<= 1) v += __shfl_xor(v, off);
  int w = threadIdx.x >> 6;
  if ((threadIdx.x & 63) == 0) red[w] = v;
  __syncthreads();
  return red[0] + red[1] + red[2] + red[3];
}

// ---------------- RMSNorm (q path, D=1536) fp32 -> bf16 ----------------
__global__ void k_rms_q(const float* __restrict__ X, const float* __restrict__ g, bf16* __restrict__ out) {
  __shared__ float red[4];
  int row = blockIdx.x, tid = threadIdx.x;
  float v[6];
  float ss = 0.f;
#pragma unroll
  for (int j = 0; j < 6; ++j) {
    v[j] = X[(size_t)row * QL + tid + j * 256];
    ss += v[j] * v[j];
  }
  float tot = block_reduce_sum(ss, red);
  float rs = rsqrtf(tot / (float)QL + 1e-6f);
#pragma unroll
  for (int j = 0; j < 6; ++j) {
    int c = tid + j * 256;
    out[(size_t)row * QL + c] = (bf16)(v[j] * rs * g[c]);
  }
}

// ---------------- RMSNorm (kv path) + rope passthrough ----------------
__global__ void k_rms_kv(const float* __restrict__ KVC, const float* __restrict__ g,
                         bf16* __restrict__ outn, bf16* __restrict__ outr) {
  __shared__ float red[4];
  int row = blockIdx.x, tid = threadIdx.x;
  float v0 = KVC[(size_t)row * 576 + tid];
  float v1 = KVC[(size_t)row * 576 + tid + 256];
  float tot = block_reduce_sum(v0 * v0 + v1 * v1, red);
  float rs = rsqrtf(tot / (float)KVL + 1e-6f);
  outn[(size_t)row * KVL + tid] = (bf16)(v0 * rs * g[tid]);
  outn[(size_t)row * KVL + tid + 256] = (bf16)(v1 * rs * g[tid + 256]);
  if (tid < 64) outr[row * 64 + tid] = (bf16)KVC[(size_t)row * 576 + 512 + tid];
}

// ---------------- fused causal flash attention ----------------
// grid 512: h = bid&15, qb balanced pairing. 4 waves x 16 q-rows, KVBLK=64.
// V path: row-major staging (vectorized) + conflict-free LDS transpose bounce.
__global__ __launch_bounds__(256) void k_attn(const bf16* __restrict__ Q, const bf16* __restrict__ KV,
                                              const bf16* __restrict__ KR, bf16* __restrict__ O) {
  __shared__ __align__(16) bf16 Ks[64 * 200];     // [kvpos][192+8]   25.6KB
  __shared__ __align__(16) bf16 Vtmp[64 * 136];   // [kvpos][128+8]   17.4KB
  __shared__ __align__(16) bf16 Vt[128 * 72];     // [feat][64+8]     18.4KB
  __shared__ __align__(16) bf16 Ps[4 * 16 * 72];  // per-wave P        9.2KB
  int bid = blockIdx.x;
  int h = bid & 15, i = bid >> 4;
  int qb = (i < 16) ? i : 47 - i;
  int q0 = qb * 64;
  int tid = threadIdx.x, lane = tid & 63, w = tid >> 6;
  int l15 = lane & 15, l4 = lane >> 4;
  bf16* Pw = Ps + w * 16 * 72;

  // Q fragments in registers
  bf16x8 aq[6];
  int qrow = q0 + w * 16 + l15;
#pragma unroll
  for (int ks = 0; ks < 6; ++ks)
    aq[ks] = *(const bf16x8*)&Q[(size_t)qrow * 3072 + h * 192 + ks * 32 + l4 * 8];

  f32x4 oacc[8] = {};
  float m[4] = {-1e30f, -1e30f, -1e30f, -1e30f};
  float lsum[4] = {};
  int nt = qb + 1;
  for (int t = 0; t < nt; ++t) {
    // stage K tile [64][192]: cols 0..127 = k_nope, 128..191 = k_rope
#pragma unroll
    for (int it = 0; it < 6; ++it) {
      int idx = it * 256 + tid;
      int r = idx / 24, gg = idx % 24;
      int p = t * 64 + r;
      int4 val;
      if (gg < 16) val = *(const int4*)&KV[(size_t)p * 4096 + h * 256 + gg * 8];
      else         val = *(const int4*)&KR[(size_t)p * 64 + (gg - 16) * 8];
      *(int4*)&Ks[r * 200 + gg * 8] = val;
    }
    // stage V row-major [64][136] (vectorized, conflict-free)
#pragma unroll
    for (int it = 0; it < 4; ++it) {
      int idx = it * 256 + tid;
      int r = idx >> 4, dg = idx & 15;
      *(int4*)&Vtmp[r * 136 + dg * 8] =
          *(const int4*)&KV[(size_t)(t * 64 + r) * 4096 + h * 256 + 128 + dg * 8];
    }
    __syncthreads();

    // S = Q @ K^T : 16x64 per wave
    f32x4 sacc[4] = {};
    __builtin_amdgcn_s_setprio(1);
#pragma unroll
    for (int ks = 0; ks < 6; ++ks)
#pragma unroll
      for (int n = 0; n < 4; ++n) {
        bf16x8 bk = *(const bf16x8*)&Ks[(n * 16 + l15) * 200 + ks * 32 + l4 * 8];
        sacc[n] = __builtin_amdgcn_mfma_f32_16x16x32_bf16(aq[ks], bk, sacc[n], 0, 0, 0);
      }
    __builtin_amdgcn_s_setprio(0);

    // LDS transpose bounce: Vt[d][k] = Vtmp[k][d]  (overlaps with QK MFMAs above)
#pragma unroll
    for (int rep = 0; rep < 4; ++rep) {
      int id = rep * 256 + tid;
      int d = id & 127, k0 = (id >> 7) * 8;
      bf16x8 pk;
#pragma unroll
      for (int j = 0; j < 8; ++j) pk[j] = Vtmp[(k0 + j) * 136 + d];
      *(bf16x8*)&Vt[d * 72 + k0] = pk;
    }

    // scale + causal mask (diagonal tile only)
    bool lastt = (t == nt - 1);
#pragma unroll
    for (int n = 0; n < 4; ++n)
#pragma unroll
      for (int r = 0; r < 4; ++r) {
        float v = sacc[n][r] * ATTN_SCALE;
        if (lastt) {
          int col = t * 64 + n * 16 + l15;
          int rowg = q0 + w * 16 + l4 * 4 + r;
          if (col > rowg) v = -1e30f;
        }
        sacc[n][r] = v;
      }

    // online softmax
    float pv[4][4];
#pragma unroll
    for (int r = 0; r < 4; ++r) {
      float mx = fmaxf(fmaxf(sacc[0][r], sacc[1][r]), fmaxf(sacc[2][r], sacc[3][r]));
      mx = fmaxf(mx, __shfl_xor(mx, 1));
      mx = fmaxf(mx, __shfl_xor(mx, 2));
      mx = fmaxf(mx, __shfl_xor(mx, 4));
      mx = fmaxf(mx, __shfl_xor(mx, 8));
      float mn = fmaxf(m[r], mx);
      float alpha = __expf(m[r] - mn);
      m[r] = mn;
      float rsum = 0.f;
#pragma unroll
      for (int n = 0; n < 4; ++n) { pv[n][r] = __expf(sacc[n][r] - mn); rsum += pv[n][r]; }
      rsum += __shfl_xor(rsum, 1);
      rsum += __shfl_xor(rsum, 2);
      rsum += __shfl_xor(rsum, 4);
      rsum += __shfl_xor(rsum, 8);
      lsum[r] = lsum[r] * alpha + rsum;
#pragma unroll
      for (int vf = 0; vf < 8; ++vf) oacc[vf][r] *= alpha;
    }

    // P -> bf16 -> per-wave LDS (stride 72: 2-way writes, free)
#pragma unroll
    for (int n = 0; n < 4; ++n)
#pragma unroll
      for (int r = 0; r < 4; ++r)
        Pw[(l4 * 4 + r) * 72 + n * 16 + l15] = (bf16)pv[n][r];

    __syncthreads();  // Vt + P ready for all waves

    __builtin_amdgcn_s_setprio(1);
#pragma unroll
    for (int ks = 0; ks < 2; ++ks) {
      bf16x8 ap = *(const bf16x8*)&Pw[l15 * 72 + ks * 32 + l4 * 8];
#pragma unroll
      for (int vf = 0; vf < 8; ++vf) {
        bf16x8 bv = *(const bf16x8*)&Vt[(vf * 16 + l15) * 72 + ks * 32 + l4 * 8];
        oacc[vf] = __builtin_amdgcn_mfma_f32_16x16x32_bf16(ap, bv, oacc[vf], 0, 0, 0);
      }
    }
    __builtin_amdgcn_s_setprio(0);
    // no barrier here: next-iter staging writes only Ks/Vtmp, whose readers
    // all completed before the pre-PV barrier.
  }

  // epilogue
#pragma unroll
  for (int vf = 0; vf < 8; ++vf)
#pragma unroll
    for (int r = 0; r < 4; ++r) {
      int rowg = q0 + w * 16 + l4 * 4 + r;
      int col = h * 128 + vf * 16 + l15;
      O[(size_t)rowg * 2048 + col] = (bf16)(oacc[vf][r] / lsum[r]);
    }
}

extern "C" void kernel_launch(void* const* d_in, const int* in_sizes, int n_in,
                              void* d_out, int out_size, void* d_ws, size_t ws_size,
                              hipStream_t stream) {
  (void)in_sizes; (void)n_in; (void)out_size; (void)ws_size;
  const float* hidden = (const float*)d_in[0];
  const float* Wqa  = (const float*)d_in[2];
  const float* gqa  = (const float*)d_in[3];
  const float* Wqb  = (const float*)d_in[4];
  const float* Wkva = (const float*)d_in[5];
  const float* gkva = (const float*)d_in[6];
  const float* Wkvb = (const float*)d_in[7];
  const float* Wo   = (const float*)d_in[8];
  float* out = (float*)d_out;

  char* ws = (char*)d_ws;
  size_t off = 0;
  auto alloc = [&](size_t bytes) {
    char* p = ws + off;
    off += (bytes + 255) & ~(size_t)255;
    return p;
  };
  bf16* Xb     = (bf16*)alloc((size_t)SEQ * HIDDEN * 2);
  bf16* WqaT   = (bf16*)alloc((size_t)QL * HIDDEN * 2);
  bf16* WqbT   = (bf16*)alloc((size_t)(NH * DQK) * QL * 2);
  bf16* WkvaT  = (bf16*)alloc((size_t)576 * HIDDEN * 2);
  bf16* WkvbT  = (bf16*)alloc((size_t)4096 * KVL * 2);
  bf16* WoT    = (bf16*)alloc((size_t)2048 * 2048 * 2);
  float* qa    = (float*)alloc((size_t)SEQ * QL * 4);
  float* kvc   = (float*)alloc((size_t)SEQ * 576 * 4);
  bf16* qc     = (bf16*)alloc((size_t)SEQ * QL * 2);
  bf16* kvn    = (bf16*)alloc((size_t)SEQ * KVL * 2);
  bf16* krope  = (bf16*)alloc((size_t)SEQ * 64 * 2);
  bf16* Qm     = (bf16*)alloc((size_t)SEQ * 3072 * 2);
  bf16* KVm    = (bf16*)alloc((size_t)SEQ * 4096 * 2);
  bf16* Om     = (bf16*)alloc((size_t)SEQ * 2048 * 2);

  k_cvt<<<(SEQ * HIDDEN / 4 + 255) / 256, 256, 0, stream>>>(hidden, Xb, SEQ * HIDDEN);
  k_transpose<<<dim3(QL / 32, HIDDEN / 32), 256, 0, stream>>>(Wqa, WqaT, HIDDEN, QL);
  k_transpose<<<dim3(3072 / 32, QL / 32), 256, 0, stream>>>(Wqb, WqbT, QL, 3072);
  k_transpose<<<dim3(576 / 32, HIDDEN / 32), 256, 0, stream>>>(Wkva, WkvaT, HIDDEN, 576);
  k_transpose<<<dim3(4096 / 32, KVL / 32), 256, 0, stream>>>(Wkvb, WkvbT, KVL, 4096);
  k_transpose<<<dim3(2048 / 32, 2048 / 32), 256, 0, stream>>>(Wo, WoT, 2048, 2048);
  k_gemm<<<dim3(16, 12), 256, 0, stream>>>(Xb, WqaT, nullptr, qa, SEQ, QL, HIDDEN);
  k_gemm<<<dim3(16, 5), 256, 0, stream>>>(Xb, WkvaT, nullptr, kvc, SEQ, 576, HIDDEN);
  k_rms_q<<<SEQ, 256, 0, stream>>>(qa, gqa, qc);
  k_rms_kv<<<SEQ, 256, 0, stream>>>(kvc, gkva, kvn, krope);
  k_gemm<<<dim3(16, 24), 256, 0, stream>>>(qc, WqbT, Qm, nullptr, SEQ, 3072, QL);
  k_gemm<<<dim3(16, 32), 256, 0, stream>>>(kvn, WkvbT, KVm, nullptr, SEQ, 4096, KVL);
  k_attn<<<512, 256, 0, stream>>>(Qm, KVm, krope, Om);
  k_gemm<<<dim3(16, 16), 256, 0, stream>>>(Om, WoT, nullptr, out, SEQ, 2048, 2048);
}